// Round 11
// baseline (151.871 us; speedup 1.0000x reference)
//
#include <hip/hip_runtime.h>
#include <hip/hip_bf16.h>

// out = tril((2Q - tril(QK^T)K) K^T) V per (b,h): two fused causal passes of
// Y = tril(X K^T) W  (pass0: X=Q,W=K -> o2; pass1: X=2Q-o2, W=V).
// R5: s-permuted GEMM1 A-reads keep P in registers; diag-only causal mask;
//     ldsK bit5 col-XOR keeps kf reads 2-way.
// R6: double-buffered K/W tiles -> ONE barrier per iteration.
// R8b/c: wf reads hoisted to regs; setprio around MFMA clusters.
// R10: single-strip WGs (1024 = 32 bh x 32 strips), longest-first, bh=i&31
//     pins a bh's strips to one XCD. 92->79 us.
// R13/R14: 36864 B LDS (Xf direct from global; seam scratch in dead
//     ldsW[1-c]); launch_bounds min kept below natural reg use (no spill).
// R15: LDS-pipe relief. R14 showed waves 12->16 = +0: not latency-bound
//     anymore. Arithmetic: each wave read the FULL K + W^T tiles per iter
//     (operands are wave-independent) -> 80 KB LDS/WG-iter ~= 60-75% of the
//     LDS pipe at 79 us. Now each wave owns TWO 16-row groups (32 t-rows):
//     every kf/wfr b128 read feeds 2 MFMAs -> reads halve (48 KB/iter).
//     WG = 128 threads (2 waves), same 64-row strip, same grid 1024, same
//     36864 B LDS (4 WGs/CU). Commit: 4xb128 (K) + 8xb64 (W^T) per thread.
//     ~220 VGPR, legal at 2 waves/SIMD -> launch_bounds(128,2).

typedef __bf16 bf16x8 __attribute__((ext_vector_type(8)));
typedef __bf16 bf16x4 __attribute__((ext_vector_type(4)));
typedef float  f32x4  __attribute__((ext_vector_type(4)));

#define MFMA16(a, b, c) __builtin_amdgcn_mfma_f32_16x16x32_bf16((a), (b), (c), 0, 0, 0)

static constexpr int S  = 2048;
static constexpr int H  = 16;
static constexpr int D  = 64;
static constexpr int RS = 3 * H * D;   // 3072 floats between consecutive s rows
static constexpr int BN = 64;          // key rows per iteration
static constexpr int LR = 72;          // row stride (u16): 64 + 8

__global__ __launch_bounds__(128, 2)
void ttt_kernel(const float* __restrict__ qkv, float* __restrict__ out)
{
    __shared__ __bf16 ldsK[2][BN * LR];   // K tile [s][d ^ 32*((s>>3)&1)], x2
    __shared__ __bf16 ldsW[2][D  * LR];   // W^T [d][s ^ (d&56)], x2
    // total 36864 B -> LDS allows 4 WGs/CU (= 8 waves/CU at 128 threads)

    const int tid  = threadIdx.x;
    const int wv   = tid >> 6;         // 0..1
    const int lane = tid & 63;
    const int q    = lane >> 4;        // quad 0..3
    const int l16  = lane & 15;

    // mapping: rank = i>>5 ascending => p descending (longest first);
    // bh = i&31 pins all strips of a bh to one XCD (i%8 == bh%8).
    const int i  = (int)blockIdx.x;
    const int p  = 31 - (i >> 5);      // t-strip index, 64-iter strips first
    const int bh = i & 31;
    const int b  = bh >> 4;
    const int h  = bh & 15;
    const int t0 = 64 * p;             // strip rows [t0, t0+64)
    const int nP = p + 1;              // s-blocks per pass

    const float* baseQ = qkv + (size_t)b * S * RS + h * D;
    const float* baseK = baseQ + H * D;
    const float* baseV = baseQ + 2 * H * D;

    // staging coords: thread owns rows r4..r4+3, cols cb..cb+7 of 64x64 tile
    const int r4  = (tid >> 3) * 4;
    const int cb  = (tid & 7) * 8;
    const int cbK = cb ^ (((r4 >> 3) & 1) << 5);   // ldsK bit5 col swizzle
                                                   // (rows r4..r4+3 share r>>3)

    f32x4 pk[8], pv[8];   // prefetch regs: [2r,2r+1] = row r4+r cols cb..cb+7
    auto loadT = [&](f32x4* dst, const float* base, int s0) {
        const float* pg = base + (size_t)(s0 + r4) * RS + cb;
#pragma unroll
        for (int r = 0; r < 4; ++r) {
            dst[2 * r]     = *(const f32x4*)(pg + r * RS);
            dst[2 * r + 1] = *(const f32x4*)(pg + r * RS + 4);
        }
    };

    // commit prefetch regs -> LDS tile buffers (K from ksrc; W^T from wsrc)
    auto commit = [&](__bf16* K_, __bf16* W_, const f32x4* ksrc, const f32x4* wsrc) {
#pragma unroll
        for (int r = 0; r < 4; ++r) {
            bf16x8 w;
#pragma unroll
            for (int j = 0; j < 4; ++j) {
                w[j]     = (__bf16)ksrc[2 * r][j];
                w[4 + j] = (__bf16)ksrc[2 * r + 1][j];
            }
            *(bf16x8*)(K_ + (r4 + r) * LR + cbK) = w;
        }
#pragma unroll
        for (int j = 0; j < 8; ++j) {
            const int d = cb + j;
            bf16x4 w;
#pragma unroll
            for (int r = 0; r < 4; ++r)
                w[r] = (__bf16)wsrc[2 * r + (j >> 2)][j & 3];
            *(bf16x4*)(W_ + d * LR + (r4 ^ (d & 56))) = w;   // 4-aligned: d&56
        }                                                    // only hits bits>=3
    };

    loadT(pk, baseK, 0);   // tile 0 (pass 0: K only), in flight during Xf load

    // ---- X B-frags straight from global, TWO 16-row groups per wave ----
    // lane holds X[t = t0 + wv*32 + g*16 + l16][d = kt*32 + q*8 + j]
    bf16x8 Xf[2][2];   // [g][kt]
#pragma unroll
    for (int g = 0; g < 2; ++g) {
        const float* pq = baseQ + (size_t)(t0 + wv * 32 + g * 16 + l16) * RS + q * 8;
#pragma unroll
        for (int kt = 0; kt < 2; ++kt) {
            f32x4 f0 = *(const f32x4*)(pq + kt * 32);
            f32x4 f1 = *(const f32x4*)(pq + kt * 32 + 4);
#pragma unroll
            for (int j = 0; j < 4; ++j) {
                Xf[g][kt][j]     = (__bf16)f0[j];
                Xf[g][kt][4 + j] = (__bf16)f1[j];
            }
        }
    }

    // permuted K-row base: A-row m of tile mi reads physical K row
    //   (mi>>1)*32 + (m>>2)*8 + (mi&1)*4 + (m&3); per-lane part (m = l16):
    const int rp   = (l16 >> 2) * 8 + (l16 & 3);
    const int kcol = (q * 8) | (((l16 >> 2) & 1) << 5);   // disjoint bits

    const f32x4 zero4 = {0.f, 0.f, 0.f, 0.f};
    f32x4 Y[2][4];   // [g][nd]
#pragma unroll
    for (int g = 0; g < 2; ++g)
#pragma unroll
        for (int nd = 0; nd < 4; ++nd) Y[g][nd] = zero4;

    const int tg0 = t0 + wv * 32 + l16;        // g=0 row; g=1 adds 16

    // ---- prologue: commit tile 0 into buf 0 ----
    commit(ldsK[0], ldsW[0], pk, pk);  // vmcnt wait for pk here (one-time)
    __syncthreads();                   // buf 0 visible

    const int NT = 2 * nP;             // iterations across both passes

    for (int u = 0; u < NT; ++u) {
        const int c  = u & 1;
        const int sb = (u >= nP) ? (u - nP) : u;

        // ---- issue loads for tile u+1 (consumed by commit at iter bottom) ----
        if (u + 1 < NT) {
            const int np_ = (u + 1 >= nP) ? 1 : 0;
            const int nsb = (u + 1) - (np_ ? nP : 0);
            loadT(pk, baseK, nsb * BN);
            if (np_) loadT(pv, baseV, nsb * BN);
        }

        __bf16* K_ = ldsK[c];
        __bf16* W_ = ldsW[c];

        // ---- GEMM1-T (s-permuted), both row-groups share each kf read ----
        // Pt[g][mi][r] = P[s_l][t_g], s_l = (mi>>1)*32 + q*8 + (mi&1)*4 + r
        f32x4 Pt[2][4];
#pragma unroll
        for (int g = 0; g < 2; ++g)
#pragma unroll
            for (int mi = 0; mi < 4; ++mi) Pt[g][mi] = zero4;
        __builtin_amdgcn_s_setprio(1);
#pragma unroll
        for (int kt = 0; kt < 2; ++kt) {
#pragma unroll
            for (int mi = 0; mi < 4; ++mi) {
                bf16x8 kf = *(bf16x8*)(K_
                    + ((mi >> 1) * 32 + (mi & 1) * 4 + rp) * LR
                    + ((kt * 32) ^ kcol));
                Pt[0][mi] = MFMA16(kf, Xf[0][kt], Pt[0][mi]);
                Pt[1][mi] = MFMA16(kf, Xf[1][kt], Pt[1][mi]);
            }
        }
        __builtin_amdgcn_s_setprio(0);

        // ---- hoist wf reads (independent of GEMM1) -> stream under cvt ----
        bf16x8 wfr[2][4];
#pragma unroll
        for (int kt = 0; kt < 2; ++kt)
#pragma unroll
            for (int nd = 0; nd < 4; ++nd) {
                const int d = l16 + nd * 16;
                wfr[kt][nd] = *(bf16x8*)(W_ + d * LR + ((kt * 32 + q * 8) ^ (d & 56)));
            }

        // ---- in-register masked cvt -> GEMM2 A-frags ----
        // af[g][kt][b2*4+r] = P[t_g][s = kt*32 + q*8 + b2*4 + r] (masked)
        bf16x8 af[2][2];
        {
            const bool diag = (sb == nP - 1);
#pragma unroll
            for (int g = 0; g < 2; ++g) {
                const int tg = tg0 + g * 16;
#pragma unroll
                for (int kt = 0; kt < 2; ++kt) {
                    bf16x8 a;
                    if (diag) {
#pragma unroll
                        for (int b2 = 0; b2 < 2; ++b2)
#pragma unroll
                            for (int r = 0; r < 4; ++r) {
                                const int sg = sb * BN + kt * 32 + q * 8 + b2 * 4 + r;
                                a[b2 * 4 + r] = (sg <= tg) ? (__bf16)Pt[g][2 * kt + b2][r]
                                                           : (__bf16)0.0f;
                            }
                    } else {
#pragma unroll
                        for (int b2 = 0; b2 < 2; ++b2)
#pragma unroll
                            for (int r = 0; r < 4; ++r)
                                a[b2 * 4 + r] = (__bf16)Pt[g][2 * kt + b2][r];
                    }
                    af[g][kt] = a;
                }
            }
        }

        // ---- GEMM2, both row-groups share each wfr frag ----
        __builtin_amdgcn_s_setprio(1);
#pragma unroll
        for (int kt = 0; kt < 2; ++kt)
#pragma unroll
            for (int nd = 0; nd < 4; ++nd) {
                Y[0][nd] = MFMA16(af[0][kt], wfr[kt][nd], Y[0][nd]);
                Y[1][nd] = MFMA16(af[1][kt], wfr[kt][nd], Y[1][nd]);
            }
        __builtin_amdgcn_s_setprio(0);

        // ---- pass seam / epilogue ----
        if (u == nP - 1) {
            // seam scratch reuses ldsW[1-c] (dead here); wave-private 32-row
            // slice (2 waves x 32 = 64 rows); extra barrier before commit.
            __bf16* sc = ldsW[1 - c] + (wv * 32) * LR;
#pragma unroll
            for (int g = 0; g < 2; ++g)
#pragma unroll
                for (int nd = 0; nd < 4; ++nd)
#pragma unroll
                    for (int r = 0; r < 4; ++r)
                        sc[(g * 16 + q * 4 + r) * LR + l16 + nd * 16] = (__bf16)Y[g][nd][r];
#pragma unroll
            for (int g = 0; g < 2; ++g)
#pragma unroll
                for (int kt = 0; kt < 2; ++kt) {
                    bf16x8 of = *(bf16x8*)(sc + (g * 16 + l16) * LR + kt * 32 + q * 8);
#pragma unroll
                    for (int j = 0; j < 8; ++j)
                        Xf[g][kt][j] = (__bf16)(2.0f * (float)Xf[g][kt][j] - (float)of[j]);
                }
#pragma unroll
            for (int g = 0; g < 2; ++g)
#pragma unroll
                for (int nd = 0; nd < 4; ++nd) Y[g][nd] = zero4;
            __syncthreads();   // seam reads done before commit overwrites
        } else if (u == NT - 1) {
            // out[b][t][h][d] fp32
#pragma unroll
            for (int g = 0; g < 2; ++g)
#pragma unroll
                for (int nd = 0; nd < 4; ++nd)
#pragma unroll
                    for (int r = 0; r < 4; ++r) {
                        const int t = t0 + wv * 32 + g * 16 + q * 4 + r;
                        const int d = l16 + nd * 16;
                        out[(((size_t)b * S + t) * H + h) * D + d] = Y[g][nd][r];
                    }
        }

        // ---- commit tile u+1 into the other buffer; single barrier ----
        if (u + 1 < NT) {
            commit(ldsK[1 - c], ldsW[1 - c], pk, (u + 1 >= nP) ? pv : pk);
            __syncthreads();
        }
    }
}

extern "C" void kernel_launch(void* const* d_in, const int* in_sizes, int n_in,
                              void* d_out, int out_size, void* d_ws, size_t ws_size,
                              hipStream_t stream)
{
    const float* qkv = (const float*)d_in[0];
    float* out = (float*)d_out;
    ttt_kernel<<<dim3(1024), 128, 0, stream>>>(qkv, out);   // 32 strips x 32 bh
}